// Round 2
// baseline (896.182 us; speedup 1.0000x reference)
//
#include <hip/hip_runtime.h>
#include <hip/hip_bf16.h>
#include <math.h>

#define NTOK 8192
#define DIN  4096
#define HG   256
#define NE   64

#define KC   32            // k-chunk held in VGPRs
#define MB   32            // rows per block (8 per wave)
#define NITER (DIN / KC)   // 128

// ---------------------------------------------------------------------------
// GEMM1: h_out[NTOK][HG] = gelu(x @ w1^T + b1)
// lane = hidden column h (w1 per-lane, in VGPRs via LDS double buffer);
// x values wave-uniform -> s_load on the scalar pipe.
// grid = 256 m-groups x 4 h-groups = 1024 blocks, 256 thr (4 waves).
// wave w owns rows [mgrp*32 + w*8, +8); all waves share the h-group slice.
// ---------------------------------------------------------------------------
__global__ __launch_bounds__(256, 4) void gemm1_gelu_kernel(
    const float* __restrict__ x, const float* __restrict__ w1,
    const float* __restrict__ b1, float* __restrict__ h_out)
{
    const int bid  = blockIdx.x;
    const int mgrp = bid & 255;
    const int g    = bid >> 8;
    const int t    = threadIdx.x;
    const int lane = t & 63;
    const int wid  = __builtin_amdgcn_readfirstlane(t >> 6);
    const int m0   = mgrp * MB + wid * 8;
    const int hcol = g * 64 + lane;

    __shared__ float wl[2][64][KC + 1];   // pad 33 -> <=2-way (free)

    // staging: thread t covers (h = t>>2, k-segment = (t&3)*8) : 8 dwords
    const int sh = t >> 2;
    const int sk = (t & 3) * 8;
    const float* wsrc = w1 + (size_t)(g * 64 + sh) * DIN + sk;

    float acc[8];
#pragma unroll
    for (int i = 0; i < 8; ++i) acc[i] = 0.f;

    // prologue: stage chunk 0
    {
        float4 a = *(const float4*)(wsrc);
        float4 b = *(const float4*)(wsrc + 4);
        wl[0][sh][sk + 0] = a.x; wl[0][sh][sk + 1] = a.y;
        wl[0][sh][sk + 2] = a.z; wl[0][sh][sk + 3] = a.w;
        wl[0][sh][sk + 4] = b.x; wl[0][sh][sk + 5] = b.y;
        wl[0][sh][sk + 6] = b.z; wl[0][sh][sk + 7] = b.w;
    }
    __syncthreads();

    const float* xbase = x + (size_t)m0 * DIN;

    int cur = 0;
#pragma unroll 1
    for (int kb = 0; kb < NITER; ++kb) {
        // prefetch next w1 chunk into registers (overlaps with compute)
        float4 pa, pb;
        if (kb < NITER - 1) {
            const float* s = wsrc + (size_t)(kb + 1) * KC;
            pa = *(const float4*)(s);
            pb = *(const float4*)(s + 4);
        }

        // per-lane w1 fragment for this chunk (<=2-way LDS, free)
        float wr[KC];
#pragma unroll
        for (int j = 0; j < KC; ++j) wr[j] = wl[cur][lane][j];

        // two-level accumulation for fp32 fidelity
        float tacc[8];
#pragma unroll
        for (int i = 0; i < 8; ++i) tacc[i] = 0.f;

        const int k0 = kb * KC;
#pragma unroll
        for (int mg = 0; mg < 8; mg += 2) {
            const float* xr0 = xbase + (size_t)mg * DIN + k0;  // uniform -> s_load
            const float* xr1 = xr0 + DIN;
#pragma unroll
            for (int j = 0; j < KC; ++j) {
                tacc[mg]     = fmaf(wr[j], xr0[j], tacc[mg]);
                tacc[mg + 1] = fmaf(wr[j], xr1[j], tacc[mg + 1]);
            }
        }
#pragma unroll
        for (int i = 0; i < 8; ++i) acc[i] += tacc[i];

        // write next chunk to the other LDS buffer (no hazard: disjoint buf)
        if (kb < NITER - 1) {
            const int nxt = cur ^ 1;
            wl[nxt][sh][sk + 0] = pa.x; wl[nxt][sh][sk + 1] = pa.y;
            wl[nxt][sh][sk + 2] = pa.z; wl[nxt][sh][sk + 3] = pa.w;
            wl[nxt][sh][sk + 4] = pb.x; wl[nxt][sh][sk + 5] = pb.y;
            wl[nxt][sh][sk + 6] = pb.z; wl[nxt][sh][sk + 7] = pb.w;
        }
        __syncthreads();
        cur ^= 1;
    }

    // epilogue: bias + exact GELU; coalesced row-major store (256B/wave)
    const float bv = b1[hcol];
#pragma unroll
    for (int mi = 0; mi < 8; ++mi) {
        float v = acc[mi] + bv;
        float gl = 0.5f * v * (1.0f + erff(v * 0.70710678118654752440f));
        h_out[(size_t)(m0 + mi) * HG + hcol] = gl;
    }
}

// ---------------------------------------------------------------------------
// Gating: logits = h @ w2^T, softmax(64), stable top-2.
// lane = row; per-lane h[row][k] sequential float4 (L1-friendly);
// w2 wave-uniform -> s_load. Wave w computes experts [16w,16w+16);
// exchange logits via padded LDS; wave 0 finishes per-row in registers.
// d_out = [ indices(float) N*2 | gates N*2 | probs N*64 ]
// ---------------------------------------------------------------------------
__global__ __launch_bounds__(256, 4) void gating_kernel(
    const float* __restrict__ h, const float* __restrict__ w2,
    float* __restrict__ out)
{
    const int t    = threadIdx.x;
    const int lane = t & 63;
    const int wid  = __builtin_amdgcn_readfirstlane(t >> 6);
    const int row  = blockIdx.x * 64 + lane;
    const int e0   = wid * 16;

    __shared__ float lg[NE][65];

    float acc[16];
#pragma unroll
    for (int i = 0; i < 16; ++i) acc[i] = 0.f;

    const float* hrow = h + (size_t)row * HG;

#pragma unroll 1
    for (int kc = 0; kc < HG; kc += 16) {
        float a[16];
#pragma unroll
        for (int q = 0; q < 4; ++q) {
            float4 v = *(const float4*)(hrow + kc + q * 4);
            a[q * 4 + 0] = v.x; a[q * 4 + 1] = v.y;
            a[q * 4 + 2] = v.z; a[q * 4 + 3] = v.w;
        }
#pragma unroll
        for (int n = 0; n < 16; ++n) {
            const float* wr = w2 + (size_t)(e0 + n) * HG + kc;  // uniform -> s_load
#pragma unroll
            for (int j = 0; j < 16; ++j)
                acc[n] = fmaf(wr[j], a[j], acc[n]);
        }
    }
#pragma unroll
    for (int n = 0; n < 16; ++n) lg[e0 + n][lane] = acc[n];
    __syncthreads();

    if (wid == 0) {
        float l[NE];
#pragma unroll
        for (int e = 0; e < NE; ++e) l[e] = lg[e][lane];

        float mx = l[0];
#pragma unroll
        for (int e = 1; e < NE; ++e) mx = fmaxf(mx, l[e]);

        float s = 0.f;
#pragma unroll
        for (int e = 0; e < NE; ++e) { float p = expf(l[e] - mx); l[e] = p; s += p; }
        const float inv = 1.0f / s;
#pragma unroll
        for (int e = 0; e < NE; ++e) l[e] *= inv;

        // stable top-2: strict '>' => lowest index wins ties (matches lax.top_k)
        float v1 = -1.0f, v2 = -2.0f;
        int   i1 = 0,     i2 = 0;
#pragma unroll
        for (int e = 0; e < NE; ++e) {
            const float p  = l[e];
            const bool  g1 = p > v1;
            const bool  g2 = p > v2;
            const float nv2 = g1 ? v1 : (g2 ? p : v2);
            const int   ni2 = g1 ? i1 : (g2 ? e : i2);
            v1 = g1 ? p : v1;
            i1 = g1 ? e : i1;
            v2 = nv2;
            i2 = ni2;
        }

        float* out_idx  = out;
        float* out_gate = out + 2 * NTOK;
        float* out_prob = out + 4 * NTOK;
        out_idx[2 * row + 0]  = (float)i1;
        out_idx[2 * row + 1]  = (float)i2;
        out_gate[2 * row + 0] = v1;
        out_gate[2 * row + 1] = v2;

        float* pr = out_prob + (size_t)row * NE;
#pragma unroll
        for (int e = 0; e < NE; e += 4) {
            float4 v = make_float4(l[e], l[e + 1], l[e + 2], l[e + 3]);
            *(float4*)(pr + e) = v;
        }
    }
}

extern "C" void kernel_launch(void* const* d_in, const int* in_sizes, int n_in,
                              void* d_out, int out_size, void* d_ws, size_t ws_size,
                              hipStream_t stream) {
    const float* x  = (const float*)d_in[0];
    const float* w1 = (const float*)d_in[1];
    const float* b1 = (const float*)d_in[2];
    const float* w2 = (const float*)d_in[3];
    float* out = (float*)d_out;
    float* h   = (float*)d_ws;   // NTOK*HG fp32 = 8 MB scratch

    gemm1_gelu_kernel<<<1024, 256, 0, stream>>>(x, w1, b1, h);
    gating_kernel<<<128, 256, 0, stream>>>(h, w2, out);
}

// Round 3
// 151.582 us; speedup vs baseline: 5.9122x; 5.9122x over previous
//
#include <hip/hip_runtime.h>
#include <hip/hip_bf16.h>
#include <math.h>

#define NTOK 8192
#define DIN  4096
#define HG   256
#define NE   64
#define SPLITK 4
#define KSTEPS_PER_BLK 32          // 128 total ksteps of 32k, /4 splits

typedef __attribute__((ext_vector_type(8))) short short8;
typedef __attribute__((ext_vector_type(4))) float f32x4;

__device__ __forceinline__ unsigned short f2bf_rne(float f) {
    union { float f; unsigned int u; } v; v.f = f;
    unsigned int r = v.u + 0x7fffu + ((v.u >> 16) & 1u);
    return (unsigned short)(r >> 16);
}
__device__ __forceinline__ float bf2f(unsigned short b) {
    union { unsigned int u; float f; } v; v.u = ((unsigned int)b) << 16;
    return v.f;
}

typedef const __attribute__((address_space(1))) unsigned int* gptr_t;
typedef __attribute__((address_space(3))) unsigned int* lptr_t;
__device__ __forceinline__ void gload_lds16(const void* g, void* l) {
    __builtin_amdgcn_global_load_lds((gptr_t)g, (lptr_t)l, 16, 0, 0);
}

// ---------------------------------------------------------------------------
// Pre-convert w1 [HG][DIN] fp32 -> fragment-ordered bf16 hi/lo tiles.
// Global layout: w1t[kstep 0..127][chunk c 0..31][lane 0..63][j 0..7] shorts,
// where c = hl*16 + unit; value = (hi|lo) of w1[unit*16 + (lane&15)]
//                                           [kstep*32 + (lane>>4)*8 + j].
// This is the exact LDS image the GEMM wants -> global_load_lds linear copy.
// ---------------------------------------------------------------------------
__global__ __launch_bounds__(512) void convert_w1_kernel(
    const float* __restrict__ w1, unsigned short* __restrict__ w1t)
{
    const int id    = blockIdx.x * 512 + threadIdx.x;   // 512 blocks
    const int lane  = id & 63;
    const int cg    = id >> 6;           // global chunk 0..4095
    const int kstep = cg >> 5;
    const int c     = cg & 31;
    const int hl    = c >> 4;
    const int unit  = c & 15;
    const int n     = unit * 16 + (lane & 15);
    const int k     = kstep * 32 + ((lane >> 4) & 3) * 8;

    const float* src = w1 + (size_t)n * DIN + k;
    short8 v;
#pragma unroll
    for (int j = 0; j < 8; ++j) {
        float f = src[j];
        unsigned short hi = f2bf_rne(f);
        v[j] = (hl == 0) ? (short)hi : (short)f2bf_rne(f - bf2f(hi));
    }
    *(short8*)(w1t + (size_t)cg * 512 + lane * 8) = v;
}

// ---------------------------------------------------------------------------
// GEMM1 (split-K): P[s][NTOK][HG] += x(bf16x3) @ w1^T  for k-range s.
// 256 blocks = 64 m-tiles x 4 splitK, 512 thr (8 waves, 2M x 4N of 64x64).
// BK=32 (one 16x16x32 K), double-buffered LDS; B via global_load_lds of the
// pre-tiled w1t; A reg-staged + converted to bf16 hi/lo in-kernel.
// ---------------------------------------------------------------------------
__global__ __launch_bounds__(512, 2) void gemm1_mfma_kernel(
    const float* __restrict__ x, const unsigned short* __restrict__ w1t,
    float* __restrict__ P)
{
    __shared__ unsigned short As[2][2][8][512];    // 32 KB: [buf][hl][m-unit][lane*8+j]
    __shared__ unsigned short Bs[2][2][16][512];   // 64 KB: [buf][hl][n-unit][lane*8+j]

    const int bid  = blockIdx.x;
    const int mblk = bid & 63;
    const int s    = bid >> 6;
    const int t    = threadIdx.x;
    const int lane = t & 63;
    const int w    = t >> 6;          // wave 0..7
    const int wm   = w >> 2;          // 0..1
    const int wn   = w & 3;           // 0..3

    const int m_base = mblk * 128;
    const int kstep0 = s * KSTEPS_PER_BLK;

    const int ar   = t & 127;         // A staging row (threads 0..255)
    const int kh   = (t >> 7) & 1;    // which 16-k half
    const bool do_a = (t < 256);

    f32x4 acc[4][4];
#pragma unroll
    for (int i = 0; i < 4; ++i)
#pragma unroll
        for (int j = 0; j < 4; ++j) acc[i][j] = (f32x4)0.f;

#define CVT(F, VH, VL, IDX)                                                   \
    { unsigned short h_ = f2bf_rne(F); (VH)[IDX] = (short)h_;                 \
      (VL)[IDX] = (short)f2bf_rne((F) - bf2f(h_)); }

#define STAGE_A_WRITE(BUF, FA0, FA1, FA2, FA3)                                \
    {   const int unit_ = ar >> 4;                                            \
        short8 vh0, vl0, vh1, vl1;                                            \
        CVT((FA0).x, vh0, vl0, 0) CVT((FA0).y, vh0, vl0, 1)                   \
        CVT((FA0).z, vh0, vl0, 2) CVT((FA0).w, vh0, vl0, 3)                   \
        CVT((FA1).x, vh0, vl0, 4) CVT((FA1).y, vh0, vl0, 5)                   \
        CVT((FA1).z, vh0, vl0, 6) CVT((FA1).w, vh0, vl0, 7)                   \
        CVT((FA2).x, vh1, vl1, 0) CVT((FA2).y, vh1, vl1, 1)                   \
        CVT((FA2).z, vh1, vl1, 2) CVT((FA2).w, vh1, vl1, 3)                   \
        CVT((FA3).x, vh1, vl1, 4) CVT((FA3).y, vh1, vl1, 5)                   \
        CVT((FA3).z, vh1, vl1, 6) CVT((FA3).w, vh1, vl1, 7)                   \
        const int ls0 = ((kh * 2 + 0) << 4) | (ar & 15);                      \
        const int ls1 = ((kh * 2 + 1) << 4) | (ar & 15);                      \
        *(short8*)&As[BUF][0][unit_][ls0 * 8] = vh0;                          \
        *(short8*)&As[BUF][1][unit_][ls0 * 8] = vl0;                          \
        *(short8*)&As[BUF][0][unit_][ls1 * 8] = vh1;                          \
        *(short8*)&As[BUF][1][unit_][ls1 * 8] = vl1;                          \
    }

    // ---- prologue: stage tile 0 ----
    {
#pragma unroll
        for (int i = 0; i < 4; ++i) {
            const int c = w * 4 + i;
            gload_lds16(w1t + ((size_t)kstep0 * 32 + c) * 512 + lane * 8,
                        &Bs[0][c >> 4][c & 15][0]);
        }
        if (do_a) {
            const float* asrc = x + (size_t)(m_base + ar) * DIN
                                  + (size_t)kstep0 * 32 + kh * 16;
            float4 fa0 = *(const float4*)(asrc);
            float4 fa1 = *(const float4*)(asrc + 4);
            float4 fa2 = *(const float4*)(asrc + 8);
            float4 fa3 = *(const float4*)(asrc + 12);
            STAGE_A_WRITE(0, fa0, fa1, fa2, fa3)
        }
    }
    __syncthreads();

    // ---- main loop ----
#pragma unroll 1
    for (int tt = 0; tt < KSTEPS_PER_BLK; ++tt) {
        const int cur = tt & 1, nxt = cur ^ 1;

        // issue next-tile loads first (latency hides under MFMA phase)
        float4 fa0, fa1, fa2, fa3;
        if (tt < KSTEPS_PER_BLK - 1) {
            if (do_a) {
                const float* asrc = x + (size_t)(m_base + ar) * DIN
                                      + (size_t)(kstep0 + tt + 1) * 32 + kh * 16;
                fa0 = *(const float4*)(asrc);
                fa1 = *(const float4*)(asrc + 4);
                fa2 = *(const float4*)(asrc + 8);
                fa3 = *(const float4*)(asrc + 12);
            }
#pragma unroll
            for (int i = 0; i < 4; ++i) {
                const int c = w * 4 + i;
                gload_lds16(w1t + ((size_t)(kstep0 + tt + 1) * 32 + c) * 512 + lane * 8,
                            &Bs[nxt][c >> 4][c & 15][0]);
            }
        }

        // fragments (conflict-free: lane*16B consecutive)
        short8 ahf[4], alf[4], bhf[4], blf[4];
#pragma unroll
        for (int mr = 0; mr < 4; ++mr) {
            ahf[mr] = *(const short8*)&As[cur][0][wm * 4 + mr][lane * 8];
            alf[mr] = *(const short8*)&As[cur][1][wm * 4 + mr][lane * 8];
        }
#pragma unroll
        for (int nr = 0; nr < 4; ++nr) {
            bhf[nr] = *(const short8*)&Bs[cur][0][wn * 4 + nr][lane * 8];
            blf[nr] = *(const short8*)&Bs[cur][1][wn * 4 + nr][lane * 8];
        }

        // 3-pass bf16x3: Ah*Bh + Ah*Bl + Al*Bh  (48 MFMA)
#pragma unroll
        for (int mr = 0; mr < 4; ++mr)
#pragma unroll
            for (int nr = 0; nr < 4; ++nr)
                acc[mr][nr] = __builtin_amdgcn_mfma_f32_16x16x32_bf16(
                    ahf[mr], bhf[nr], acc[mr][nr], 0, 0, 0);
#pragma unroll
        for (int mr = 0; mr < 4; ++mr)
#pragma unroll
            for (int nr = 0; nr < 4; ++nr)
                acc[mr][nr] = __builtin_amdgcn_mfma_f32_16x16x32_bf16(
                    ahf[mr], blf[nr], acc[mr][nr], 0, 0, 0);
#pragma unroll
        for (int mr = 0; mr < 4; ++mr)
#pragma unroll
            for (int nr = 0; nr < 4; ++nr)
                acc[mr][nr] = __builtin_amdgcn_mfma_f32_16x16x32_bf16(
                    alf[mr], bhf[nr], acc[mr][nr], 0, 0, 0);

        // write converted A for next tile
        if (tt < KSTEPS_PER_BLK - 1 && do_a) {
            STAGE_A_WRITE(nxt, fa0, fa1, fa2, fa3)
        }
        __syncthreads();
    }

    // ---- epilogue: store fp32 partial ----
    float* pb = P + (size_t)s * ((size_t)NTOK * HG);
#pragma unroll
    for (int mr = 0; mr < 4; ++mr)
#pragma unroll
        for (int nr = 0; nr < 4; ++nr) {
            const int n = wn * 64 + nr * 16 + (lane & 15);
#pragma unroll
            for (int r = 0; r < 4; ++r) {
                const int m = m_base + wm * 64 + mr * 16 + ((lane >> 4) & 3) * 4 + r;
                pb[(size_t)m * HG + n] = acc[mr][nr][r];
            }
        }
#undef STAGE_A_WRITE
#undef CVT
}

// ---------------------------------------------------------------------------
// Reduce 4 split-K partials + bias + exact GELU -> h_t[HG][NTOK] (transposed).
// 128 blocks x 256 thr; thread = one h column, 64 rows; coalesced both ways.
// ---------------------------------------------------------------------------
__global__ __launch_bounds__(256) void reduce_gelu_kernel(
    const float* __restrict__ P, const float* __restrict__ b1,
    float* __restrict__ h_t)
{
    const int hcol = threadIdx.x;
    const int r0   = blockIdx.x * 64;
    const float bv = b1[hcol];
    const size_t SS = (size_t)NTOK * HG;

    float v[64];
#pragma unroll
    for (int i = 0; i < 64; ++i) {
        const size_t off = (size_t)(r0 + i) * HG + hcol;
        float q = P[off] + P[off + SS] + P[off + 2 * SS] + P[off + 3 * SS] + bv;
        v[i] = 0.5f * q * (1.0f + erff(q * 0.70710678118654752440f));
    }
    float* dst = h_t + (size_t)hcol * NTOK + r0;
#pragma unroll
    for (int i = 0; i < 64; i += 4)
        *(float4*)(dst + i) = make_float4(v[i], v[i + 1], v[i + 2], v[i + 3]);
}

// ---------------------------------------------------------------------------
// Gating: logits = h @ w2^T, softmax(64), stable top-2.
// h_t transposed -> lane=row reads coalesced. 8 waves x 8 experts.
// d_out = [ indices(float) N*2 | gates N*2 | probs N*64 ]
// ---------------------------------------------------------------------------
__global__ __launch_bounds__(512) void gating_kernel(
    const float* __restrict__ h_t, const float* __restrict__ w2,
    float* __restrict__ out)
{
    const int t    = threadIdx.x;
    const int lane = t & 63;
    const int w    = t >> 6;
    const int row  = blockIdx.x * 64 + lane;
    const int e0   = w * 8;

    __shared__ float lg[NE][65];

    float acc[8];
#pragma unroll
    for (int i = 0; i < 8; ++i) acc[i] = 0.f;

#pragma unroll 1
    for (int kc = 0; kc < HG; kc += 16) {
        float a[16];
#pragma unroll
        for (int j = 0; j < 16; ++j)
            a[j] = h_t[(size_t)(kc + j) * NTOK + row];   // coalesced
#pragma unroll
        for (int n = 0; n < 8; ++n) {
            const float* wr = w2 + (size_t)(e0 + n) * HG + kc;  // uniform -> s_load
#pragma unroll
            for (int j = 0; j < 16; ++j)
                acc[n] = fmaf(wr[j], a[j], acc[n]);
        }
    }
#pragma unroll
    for (int n = 0; n < 8; ++n) lg[e0 + n][lane] = acc[n];
    __syncthreads();

    if (w == 0) {
        float l[NE];
#pragma unroll
        for (int e = 0; e < NE; ++e) l[e] = lg[e][lane];

        float mx = l[0];
#pragma unroll
        for (int e = 1; e < NE; ++e) mx = fmaxf(mx, l[e]);

        float ssum = 0.f;
#pragma unroll
        for (int e = 0; e < NE; ++e) { float p = expf(l[e] - mx); l[e] = p; ssum += p; }
        const float inv = 1.0f / ssum;
#pragma unroll
        for (int e = 0; e < NE; ++e) l[e] *= inv;

        float v1 = -1.0f, v2 = -2.0f;
        int   i1 = 0,     i2 = 0;
#pragma unroll
        for (int e = 0; e < NE; ++e) {
            const float p  = l[e];
            const bool  g1 = p > v1;
            const bool  g2 = p > v2;
            const float nv2 = g1 ? v1 : (g2 ? p : v2);
            const int   ni2 = g1 ? i1 : (g2 ? e : i2);
            v1 = g1 ? p : v1;
            i1 = g1 ? e : i1;
            v2 = nv2;
            i2 = ni2;
        }

        float* out_idx  = out;
        float* out_gate = out + 2 * NTOK;
        float* out_prob = out + 4 * NTOK;
        out_idx[2 * row + 0]  = (float)i1;
        out_idx[2 * row + 1]  = (float)i2;
        out_gate[2 * row + 0] = v1;
        out_gate[2 * row + 1] = v2;

        float* pr = out_prob + (size_t)row * NE;
#pragma unroll
        for (int e = 0; e < NE; e += 4)
            *(float4*)(pr + e) = make_float4(l[e], l[e + 1], l[e + 2], l[e + 3]);
    }
}

extern "C" void kernel_launch(void* const* d_in, const int* in_sizes, int n_in,
                              void* d_out, int out_size, void* d_ws, size_t ws_size,
                              hipStream_t stream) {
    const float* x  = (const float*)d_in[0];
    const float* w1 = (const float*)d_in[1];
    const float* b1 = (const float*)d_in[2];
    const float* w2 = (const float*)d_in[3];
    float* out = (float*)d_out;

    // workspace layout: w1t (4 MB) | P (32 MB) | h_t (8 MB)  = 44 MB
    unsigned short* w1t = (unsigned short*)d_ws;
    float* P   = (float*)((char*)d_ws + (4u << 20));
    float* h_t = (float*)((char*)d_ws + (36u << 20));

    convert_w1_kernel<<<512, 512, 0, stream>>>(w1, w1t);
    gemm1_mfma_kernel<<<256, 512, 0, stream>>>(x, w1t, P);
    reduce_gelu_kernel<<<128, 256, 0, stream>>>(P, b1, h_t);
    gating_kernel<<<128, 512, 0, stream>>>(h_t, w2, out);
}

// Round 4
// 134.482 us; speedup vs baseline: 6.6640x; 1.1272x over previous
//
#include <hip/hip_runtime.h>
#include <hip/hip_bf16.h>
#include <math.h>

#define NTOK 8192
#define DIN  4096
#define HG   256
#define NE   64
#define SPLITK 4
#define KSTEPS 32          // ksteps of 32 per split

typedef __attribute__((ext_vector_type(8))) short short8;
typedef __attribute__((ext_vector_type(4))) float f32x4;

__device__ __forceinline__ unsigned short f2bf_rne(float f) {
    union { float f; unsigned int u; } v; v.f = f;
    unsigned int r = v.u + 0x7fffu + ((v.u >> 16) & 1u);
    return (unsigned short)(r >> 16);
}
__device__ __forceinline__ float bf2f(unsigned short b) {
    union { unsigned int u; float f; } v; v.u = ((unsigned int)b) << 16;
    return v.f;
}

typedef const __attribute__((address_space(1))) unsigned int* gptr_t;
typedef __attribute__((address_space(3))) unsigned int* lptr_t;
__device__ __forceinline__ void gload_lds16(const void* g, void* l) {
    __builtin_amdgcn_global_load_lds((gptr_t)g, (lptr_t)l, 16, 0, 0);
}

// ---------------------------------------------------------------------------
// Pre-convert w1 [HG][DIN] fp32 -> fragment-ordered bf16 hi/lo tiles.
// w1t[kstep][c][lane][j]: c = hl*16+unit; value = (hi|lo) of
// w1[unit*16 + (lane&15)][kstep*32 + (lane>>4)*8 + j].   (validated r3)
// ---------------------------------------------------------------------------
__global__ __launch_bounds__(512) void convert_w1_kernel(
    const float* __restrict__ w1, unsigned short* __restrict__ w1t)
{
    const int id    = blockIdx.x * 512 + threadIdx.x;
    const int lane  = id & 63;
    const int cg    = id >> 6;           // 0..4095
    const int kstep = cg >> 5;
    const int c     = cg & 31;
    const int hl    = c >> 4;
    const int unit  = c & 15;
    const int n     = unit * 16 + (lane & 15);
    const int k     = kstep * 32 + ((lane >> 4) & 3) * 8;

    const float* src = w1 + (size_t)n * DIN + k;
    short8 v;
#pragma unroll
    for (int j = 0; j < 8; ++j) {
        float f = src[j];
        unsigned short hi = f2bf_rne(f);
        v[j] = (hl == 0) ? (short)hi : (short)f2bf_rne(f - bf2f(hi));
    }
    *(short8*)(w1t + (size_t)cg * 512 + lane * 8) = v;
}

// ---------------------------------------------------------------------------
// GEMM1 (split-K): P[s][NTOK][HG] = x(bf16x3) @ w1^T for k-range s.
// 256 blocks = 64 m-tiles x 4 splitK, 512 thr (8 waves: 2M x 4N of 64x64).
// As single-buffered (16 KB) + reg double-buffer (T14); Bs double (64 KB).
// A staging: all 512 threads, 8 floats each, contiguous 32 B.
// ---------------------------------------------------------------------------
__global__ __launch_bounds__(512, 2) void gemm1_mfma_kernel(
    const float* __restrict__ x, const unsigned short* __restrict__ w1t,
    float* __restrict__ P)
{
    __shared__ unsigned short As[2][8][512];     // [hl][unit][ls*8+j] : 16 KB
    __shared__ unsigned short Bs[2][2][16][512]; // [buf][hl][unit][..] : 64 KB

    const int bid  = blockIdx.x;
    const int mblk = bid & 63;
    const int s    = bid >> 6;
    const int t    = threadIdx.x;
    const int lane = t & 63;
    const int w    = t >> 6;
    const int wm   = w >> 2;
    const int wn   = w & 3;

    const int m_base = mblk * 128;
    const int kstep0 = s * KSTEPS;

    // A staging: thread t -> row R, k-segment kseg (8 floats, 32 B contiguous)
    const int R     = t >> 2;             // 0..127
    const int kseg  = t & 3;              // *8
    const int aunit = R >> 4;             // == wave id
    const int als   = (kseg << 4) | (R & 15);
    const float* asrc = x + (size_t)(m_base + R) * DIN
                          + (size_t)kstep0 * 32 + kseg * 8;

    f32x4 acc[4][4];
#pragma unroll
    for (int i = 0; i < 4; ++i)
#pragma unroll
        for (int j = 0; j < 4; ++j) acc[i][j] = (f32x4)0.f;

#define CVT8_STORE(F0, F1)                                                    \
    {   short8 vh_, vl_;                                                      \
        float ff_[8] = { (F0).x, (F0).y, (F0).z, (F0).w,                      \
                         (F1).x, (F1).y, (F1).z, (F1).w };                    \
        _Pragma("unroll")                                                     \
        for (int j_ = 0; j_ < 8; ++j_) {                                      \
            unsigned short h_ = f2bf_rne(ff_[j_]);                            \
            vh_[j_] = (short)h_;                                              \
            vl_[j_] = (short)f2bf_rne(ff_[j_] - bf2f(h_));                    \
        }                                                                     \
        *(short8*)&As[0][aunit][als * 8] = vh_;                               \
        *(short8*)&As[1][aunit][als * 8] = vl_;                               \
    }

    // ---- prologue: issue B0, load+convert A0 ----
#pragma unroll
    for (int i = 0; i < 4; ++i) {
        const int c = w * 4 + i;
        gload_lds16(w1t + ((size_t)kstep0 * 32 + c) * 512 + lane * 8,
                    &Bs[0][c >> 4][c & 15][0]);
    }
    {
        float4 a0 = *(const float4*)(asrc);
        float4 a1 = *(const float4*)(asrc + 4);
        CVT8_STORE(a0, a1)
    }
    __syncthreads();

    // ---- main loop ----
#pragma unroll 1
    for (int tt = 0; tt < KSTEPS; ++tt) {
        const int bcur = tt & 1, bnxt = bcur ^ 1;
        const bool last = (tt == KSTEPS - 1);

        // issue next-tile loads first (in flight across the MFMA phase)
        float4 na0, na1;
        if (!last) {
            const float* ap = asrc + (size_t)(tt + 1) * 32;
            na0 = *(const float4*)(ap);
            na1 = *(const float4*)(ap + 4);
#pragma unroll
            for (int i = 0; i < 4; ++i) {
                const int c = w * 4 + i;
                gload_lds16(w1t + ((size_t)(kstep0 + tt + 1) * 32 + c) * 512 + lane * 8,
                            &Bs[bnxt][c >> 4][c & 15][0]);
            }
        }

        // fragments (conflict-free: lane*16B contiguous)
        short8 ahf[4], alf[4], bhf[4], blf[4];
#pragma unroll
        for (int mr = 0; mr < 4; ++mr) {
            ahf[mr] = *(const short8*)&As[0][wm * 4 + mr][lane * 8];
            alf[mr] = *(const short8*)&As[1][wm * 4 + mr][lane * 8];
        }
#pragma unroll
        for (int nr = 0; nr < 4; ++nr) {
            bhf[nr] = *(const short8*)&Bs[bcur][0][wn * 4 + nr][lane * 8];
            blf[nr] = *(const short8*)&Bs[bcur][1][wn * 4 + nr][lane * 8];
        }

        // bf16x3: Ah*Bh + Ah*Bl + Al*Bh
#pragma unroll
        for (int mr = 0; mr < 4; ++mr)
#pragma unroll
            for (int nr = 0; nr < 4; ++nr)
                acc[mr][nr] = __builtin_amdgcn_mfma_f32_16x16x32_bf16(
                    ahf[mr], bhf[nr], acc[mr][nr], 0, 0, 0);
#pragma unroll
        for (int mr = 0; mr < 4; ++mr)
#pragma unroll
            for (int nr = 0; nr < 4; ++nr)
                acc[mr][nr] = __builtin_amdgcn_mfma_f32_16x16x32_bf16(
                    ahf[mr], blf[nr], acc[mr][nr], 0, 0, 0);
#pragma unroll
        for (int mr = 0; mr < 4; ++mr)
#pragma unroll
            for (int nr = 0; nr < 4; ++nr)
                acc[mr][nr] = __builtin_amdgcn_mfma_f32_16x16x32_bf16(
                    alf[mr], bhf[nr], acc[mr][nr], 0, 0, 0);

        __syncthreads();                 // all waves done reading As
        if (!last) { CVT8_STORE(na0, na1) }   // write-late (T14)
        __syncthreads();                 // As ready; Bs[bnxt] drained
    }
#undef CVT8_STORE

    // ---- epilogue: store fp32 partial (validated r3) ----
    float* pb = P + (size_t)s * ((size_t)NTOK * HG);
#pragma unroll
    for (int mr = 0; mr < 4; ++mr)
#pragma unroll
        for (int nr = 0; nr < 4; ++nr) {
            const int n = wn * 64 + nr * 16 + (lane & 15);
#pragma unroll
            for (int r = 0; r < 4; ++r) {
                const int m = m_base + wm * 64 + mr * 16 + ((lane >> 4) & 3) * 4 + r;
                pb[(size_t)m * HG + n] = acc[mr][nr][r];
            }
        }
}

// ---------------------------------------------------------------------------
// Fused tail: reduce 4 split-K partials + bias + exact GELU -> h in LDS,
// then logits = h @ w2^T, softmax(64), stable top-2.
// 128 blocks x 512 thr, 64 rows each.
// d_out = [ indices(float) N*2 | gates N*2 | probs N*64 ]
// ---------------------------------------------------------------------------
__global__ __launch_bounds__(512) void reduce_gate_kernel(
    const float* __restrict__ P, const float* __restrict__ b1,
    const float* __restrict__ w2, float* __restrict__ out)
{
    __shared__ float h_lds[64][257];   // (r+k)&31 banks -> 2-way free reads
    __shared__ float lg[NE][65];

    const int t    = threadIdx.x;
    const int lane = t & 63;
    const int w    = t >> 6;
    const int r0   = blockIdx.x * 64;
    const size_t SS = (size_t)NTOK * HG;

    // ---- phase 1: reduce + bias + gelu ----
    {
        const int R  = t >> 3;           // 0..63
        const int k0 = (t & 7) * 32;
        const size_t base = (size_t)(r0 + R) * HG + k0;
#pragma unroll
        for (int j = 0; j < 32; j += 4) {
            float4 v0 = *(const float4*)(P + base + j);
            float4 v1 = *(const float4*)(P + base + SS + j);
            float4 v2 = *(const float4*)(P + base + 2 * SS + j);
            float4 v3 = *(const float4*)(P + base + 3 * SS + j);
            float4 bb = *(const float4*)(b1 + k0 + j);
            float q[4] = { v0.x + v1.x + v2.x + v3.x + bb.x,
                           v0.y + v1.y + v2.y + v3.y + bb.y,
                           v0.z + v1.z + v2.z + v3.z + bb.z,
                           v0.w + v1.w + v2.w + v3.w + bb.w };
#pragma unroll
            for (int c = 0; c < 4; ++c) {
                float g = 0.5f * q[c] *
                          (1.0f + erff(q[c] * 0.70710678118654752440f));
                h_lds[R][k0 + j + c] = g;
            }
        }
    }
    __syncthreads();

    // ---- phase 2: logits; wave w -> experts [8w, 8w+8), lane = row ----
    const int e0 = w * 8;
    float acc[8];
#pragma unroll
    for (int i = 0; i < 8; ++i) acc[i] = 0.f;

#pragma unroll 1
    for (int kc = 0; kc < HG; kc += 16) {
        float a[16];
#pragma unroll
        for (int j = 0; j < 16; ++j) a[j] = h_lds[lane][kc + j];
#pragma unroll
        for (int n = 0; n < 8; ++n) {
            const float* wr = w2 + (size_t)(e0 + n) * HG + kc;  // uniform -> s_load
#pragma unroll
            for (int j = 0; j < 16; ++j)
                acc[n] = fmaf(wr[j], a[j], acc[n]);
        }
    }
#pragma unroll
    for (int n = 0; n < 8; ++n) lg[e0 + n][lane] = acc[n];
    __syncthreads();

    // ---- phase 3: softmax + stable top-2 (wave 0), validated r1-r3 ----
    if (w == 0) {
        float l[NE];
#pragma unroll
        for (int e = 0; e < NE; ++e) l[e] = lg[e][lane];

        float mx = l[0];
#pragma unroll
        for (int e = 1; e < NE; ++e) mx = fmaxf(mx, l[e]);

        float ssum = 0.f;
#pragma unroll
        for (int e = 0; e < NE; ++e) { float p = expf(l[e] - mx); l[e] = p; ssum += p; }
        const float inv = 1.0f / ssum;
#pragma unroll
        for (int e = 0; e < NE; ++e) l[e] *= inv;

        float v1 = -1.0f, v2 = -2.0f;
        int   i1 = 0,     i2 = 0;
#pragma unroll
        for (int e = 0; e < NE; ++e) {
            const float p  = l[e];
            const bool  g1 = p > v1;
            const bool  g2 = p > v2;
            const float nv2 = g1 ? v1 : (g2 ? p : v2);
            const int   ni2 = g1 ? i1 : (g2 ? e : i2);
            v1 = g1 ? p : v1;
            i1 = g1 ? e : i1;
            v2 = nv2;
            i2 = ni2;
        }

        const int row = r0 + lane;
        float* out_idx  = out;
        float* out_gate = out + 2 * NTOK;
        float* out_prob = out + 4 * NTOK;
        out_idx[2 * row + 0]  = (float)i1;
        out_idx[2 * row + 1]  = (float)i2;
        out_gate[2 * row + 0] = v1;
        out_gate[2 * row + 1] = v2;

        float* pr = out_prob + (size_t)row * NE;
#pragma unroll
        for (int e = 0; e < NE; e += 4)
            *(float4*)(pr + e) = make_float4(l[e], l[e + 1], l[e + 2], l[e + 3]);
    }
}

extern "C" void kernel_launch(void* const* d_in, const int* in_sizes, int n_in,
                              void* d_out, int out_size, void* d_ws, size_t ws_size,
                              hipStream_t stream) {
    const float* x  = (const float*)d_in[0];
    const float* w1 = (const float*)d_in[1];
    const float* b1 = (const float*)d_in[2];
    const float* w2 = (const float*)d_in[3];
    float* out = (float*)d_out;

    // workspace: w1t (4 MB) | P (32 MB)  = 36 MB
    unsigned short* w1t = (unsigned short*)d_ws;
    float* P = (float*)((char*)d_ws + (4u << 20));

    convert_w1_kernel<<<512, 512, 0, stream>>>(w1, w1t);
    gemm1_mfma_kernel<<<256, 512, 0, stream>>>(x, w1t, P);
    reduce_gate_kernel<<<128, 512, 0, stream>>>(P, b1, w2, out);
}

// Round 5
// 124.680 us; speedup vs baseline: 7.1878x; 1.0786x over previous
//
#include <hip/hip_runtime.h>
#include <hip/hip_bf16.h>
#include <math.h>

#define NTOK 8192
#define DIN  4096
#define HG   256
#define NE   64
#define SPLITK 4
#define KSTEPS 32          // ksteps of 32 per split (4096/4/32)

typedef __attribute__((ext_vector_type(8))) short short8;
typedef __attribute__((ext_vector_type(4))) short short4v;
typedef __attribute__((ext_vector_type(4))) float f32x4;

__device__ __forceinline__ unsigned short f2bf_rne(float f) {
    union { float f; unsigned int u; } v; v.f = f;
    unsigned int r = v.u + 0x7fffu + ((v.u >> 16) & 1u);
    return (unsigned short)(r >> 16);
}
__device__ __forceinline__ float bf2f(unsigned short b) {
    union { unsigned int u; float f; } v; v.u = ((unsigned int)b) << 16;
    return v.f;
}

typedef const __attribute__((address_space(1))) unsigned int* gptr_t;
typedef __attribute__((address_space(3))) unsigned int* lptr_t;
__device__ __forceinline__ void gload_lds16(const void* g, void* l) {
    __builtin_amdgcn_global_load_lds((gptr_t)g, (lptr_t)l, 16, 0, 0);
}

// ---------------------------------------------------------------------------
// Pre-convert w1 [HG][DIN] fp32 -> fragment-ordered bf16 hi/lo tiles.
// w1t[kstep][c][lane][j]: c = hl*16+unit; value = (hi|lo) of
// w1[unit*16 + (lane&15)][kstep*32 + (lane>>4)*8 + j].   (validated r3/r4)
// ---------------------------------------------------------------------------
__global__ __launch_bounds__(512) void convert_w1_kernel(
    const float* __restrict__ w1, unsigned short* __restrict__ w1t)
{
    const int id    = blockIdx.x * 512 + threadIdx.x;
    const int lane  = id & 63;
    const int cg    = id >> 6;           // 0..4095
    const int kstep = cg >> 5;
    const int c     = cg & 31;
    const int hl    = c >> 4;
    const int unit  = c & 15;
    const int n     = unit * 16 + (lane & 15);
    const int k     = kstep * 32 + ((lane >> 4) & 3) * 8;

    const float* src = w1 + (size_t)n * DIN + k;
    short8 v;
#pragma unroll
    for (int j = 0; j < 8; ++j) {
        float f = src[j];
        unsigned short hi = f2bf_rne(f);
        v[j] = (hl == 0) ? (short)hi : (short)f2bf_rne(f - bf2f(hi));
    }
    *(short8*)(w1t + (size_t)cg * 512 + lane * 8) = v;
}

// ---------------------------------------------------------------------------
// GEMM1 (split-K): P[s][NTOK][HG] = x(bf16x3) @ w1^T for k-range s.
// 512 blocks = 128 m-tiles (BM=64) x 4 splitK; 512 thr = 8 waves (2M x 4N of
// 32x64 wave tiles). LDS 72 KB -> 2 blocks/CU (4 waves/SIMD).
// As single-buffered + reg prefetch (T14); Bs double via global_load_lds.
// A staging: thread t -> (unit=t>>7, slot=(t>>1)&63, half=t&1) so wave w,
// lane l writes LDS byte w*512 + l*8  == lane-contiguous -> conflict-free.
// ---------------------------------------------------------------------------
__global__ __launch_bounds__(512, 4) void gemm1_mfma_kernel(
    const float* __restrict__ x, const unsigned short* __restrict__ w1t,
    float* __restrict__ P)
{
    __shared__ unsigned short As[2][4][512];     // [hl][unit][slot*8+j] : 8 KB
    __shared__ unsigned short Bs[2][2][16][512]; // [buf][hl][unit][...] : 64 KB

    const int bid  = blockIdx.x;
    const int mblk = bid & 127;
    const int s    = bid >> 7;
    const int t    = threadIdx.x;
    const int lane = t & 63;
    const int w    = t >> 6;
    const int wm   = w >> 2;          // 0..1
    const int wn   = w & 3;           // 0..3

    const int m_base = mblk * 64;
    const int kstep0 = s * KSTEPS;

    // A staging map (bijective t <-> (unit,slot,half))
    const int a_unit = t >> 7;            // 0..3
    const int a_slot = (t >> 1) & 63;     // 0..63 : (kseg<<4)|row15
    const int a_half = t & 1;
    const int a_row  = a_unit * 16 + (a_slot & 15);
    const int a_koff = (a_slot >> 4) * 8 + a_half * 4;
    const float* asrc = x + (size_t)(m_base + a_row) * DIN
                          + (size_t)kstep0 * 32 + a_koff;
    const int a_ldso = a_slot * 8 + a_half * 4;   // shorts within As[hl][unit]

    f32x4 acc[2][4];
#pragma unroll
    for (int i = 0; i < 2; ++i)
#pragma unroll
        for (int j = 0; j < 4; ++j) acc[i][j] = (f32x4)0.f;

#define CVT4_STORE(F)                                                         \
    {   short4v vh_, vl_;                                                     \
        float ff_[4] = { (F).x, (F).y, (F).z, (F).w };                        \
        _Pragma("unroll")                                                     \
        for (int j_ = 0; j_ < 4; ++j_) {                                      \
            unsigned short h_ = f2bf_rne(ff_[j_]);                            \
            vh_[j_] = (short)h_;                                              \
            vl_[j_] = (short)f2bf_rne(ff_[j_] - bf2f(h_));                    \
        }                                                                     \
        *(short4v*)&As[0][a_unit][a_ldso] = vh_;                              \
        *(short4v*)&As[1][a_unit][a_ldso] = vl_;                              \
    }

    // ---- prologue: issue B0 gloads, load+convert A0 ----
#pragma unroll
    for (int i = 0; i < 4; ++i) {
        const int c = w * 4 + i;
        gload_lds16(w1t + ((size_t)kstep0 * 32 + c) * 512 + lane * 8,
                    &Bs[0][c >> 4][c & 15][0]);
    }
    {
        float4 a0 = *(const float4*)(asrc);
        CVT4_STORE(a0)
    }
    __syncthreads();

    // ---- main loop ----
#pragma unroll 1
    for (int tt = 0; tt < KSTEPS; ++tt) {
        const int bcur = tt & 1, bnxt = bcur ^ 1;
        const bool last = (tt == KSTEPS - 1);

        // issue next-tile loads first: they fly across the MFMA phase
        float4 nx;
        if (!last) {
            nx = *(const float4*)(asrc + (size_t)(tt + 1) * 32);
#pragma unroll
            for (int i = 0; i < 4; ++i) {
                const int c = w * 4 + i;
                gload_lds16(w1t + ((size_t)(kstep0 + tt + 1) * 32 + c) * 512 + lane * 8,
                            &Bs[bnxt][c >> 4][c & 15][0]);
            }
        }

        // fragments (lane*16B contiguous -> conflict-free)
        short8 ahf[2], alf[2], bhf[4], blf[4];
#pragma unroll
        for (int mr = 0; mr < 2; ++mr) {
            ahf[mr] = *(const short8*)&As[0][wm * 2 + mr][lane * 8];
            alf[mr] = *(const short8*)&As[1][wm * 2 + mr][lane * 8];
        }
#pragma unroll
        for (int nr = 0; nr < 4; ++nr) {
            bhf[nr] = *(const short8*)&Bs[bcur][0][wn * 4 + nr][lane * 8];
            blf[nr] = *(const short8*)&Bs[bcur][1][wn * 4 + nr][lane * 8];
        }

        // bf16x3: Ah*Bh + Ah*Bl + Al*Bh   (24 MFMA)
#pragma unroll
        for (int mr = 0; mr < 2; ++mr)
#pragma unroll
            for (int nr = 0; nr < 4; ++nr)
                acc[mr][nr] = __builtin_amdgcn_mfma_f32_16x16x32_bf16(
                    ahf[mr], bhf[nr], acc[mr][nr], 0, 0, 0);
#pragma unroll
        for (int mr = 0; mr < 2; ++mr)
#pragma unroll
            for (int nr = 0; nr < 4; ++nr)
                acc[mr][nr] = __builtin_amdgcn_mfma_f32_16x16x32_bf16(
                    ahf[mr], blf[nr], acc[mr][nr], 0, 0, 0);
#pragma unroll
        for (int mr = 0; mr < 2; ++mr)
#pragma unroll
            for (int nr = 0; nr < 4; ++nr)
                acc[mr][nr] = __builtin_amdgcn_mfma_f32_16x16x32_bf16(
                    alf[mr], bhf[nr], acc[mr][nr], 0, 0, 0);

        if (!last) {
            __syncthreads();            // all waves done reading As
            CVT4_STORE(nx)              // write-late (T14), conflict-free
            __syncthreads();            // As ready; Bs[bnxt] drained (vmcnt)
        }
    }
#undef CVT4_STORE

    // ---- epilogue: store fp32 partial ----
    float* pb = P + (size_t)s * ((size_t)NTOK * HG);
#pragma unroll
    for (int mr = 0; mr < 2; ++mr)
#pragma unroll
        for (int nr = 0; nr < 4; ++nr) {
            const int n = wn * 64 + nr * 16 + (lane & 15);
#pragma unroll
            for (int r = 0; r < 4; ++r) {
                const int m = m_base + wm * 32 + mr * 16 + ((lane >> 4) & 3) * 4 + r;
                pb[(size_t)m * HG + n] = acc[mr][nr][r];
            }
        }
}

// ---------------------------------------------------------------------------
// Fused tail: reduce 4 split-K partials + bias + exact GELU -> h in LDS,
// then logits = h @ w2^T, softmax(64), stable top-2.  (validated r4)
// d_out = [ indices(float) N*2 | gates N*2 | probs N*64 ]
// ---------------------------------------------------------------------------
__global__ __launch_bounds__(512) void reduce_gate_kernel(
    const float* __restrict__ P, const float* __restrict__ b1,
    const float* __restrict__ w2, float* __restrict__ out)
{
    __shared__ float h_lds[64][257];
    __shared__ float lg[NE][65];

    const int t    = threadIdx.x;
    const int lane = t & 63;
    const int w    = t >> 6;
    const int r0   = blockIdx.x * 64;
    const size_t SS = (size_t)NTOK * HG;

    // ---- phase 1: reduce + bias + gelu ----
    {
        const int R  = t >> 3;           // 0..63
        const int k0 = (t & 7) * 32;
        const size_t base = (size_t)(r0 + R) * HG + k0;
#pragma unroll
        for (int j = 0; j < 32; j += 4) {
            float4 v0 = *(const float4*)(P + base + j);
            float4 v1 = *(const float4*)(P + base + SS + j);
            float4 v2 = *(const float4*)(P + base + 2 * SS + j);
            float4 v3 = *(const float4*)(P + base + 3 * SS + j);
            float4 bb = *(const float4*)(b1 + k0 + j);
            float q[4] = { v0.x + v1.x + v2.x + v3.x + bb.x,
                           v0.y + v1.y + v2.y + v3.y + bb.y,
                           v0.z + v1.z + v2.z + v3.z + bb.z,
                           v0.w + v1.w + v2.w + v3.w + bb.w };
#pragma unroll
            for (int c = 0; c < 4; ++c) {
                float g = 0.5f * q[c] *
                          (1.0f + erff(q[c] * 0.70710678118654752440f));
                h_lds[R][k0 + j + c] = g;
            }
        }
    }
    __syncthreads();

    // ---- phase 2: logits; wave w -> experts [8w, 8w+8), lane = row ----
    const int e0 = w * 8;
    float acc[8];
#pragma unroll
    for (int i = 0; i < 8; ++i) acc[i] = 0.f;

#pragma unroll 1
    for (int kc = 0; kc < HG; kc += 16) {
        float a[16];
#pragma unroll
        for (int j = 0; j < 16; ++j) a[j] = h_lds[lane][kc + j];
#pragma unroll
        for (int n = 0; n < 8; ++n) {
            const float* wr = w2 + (size_t)(e0 + n) * HG + kc;  // uniform -> s_load
#pragma unroll
            for (int j = 0; j < 16; ++j)
                acc[n] = fmaf(wr[j], a[j], acc[n]);
        }
    }
#pragma unroll
    for (int n = 0; n < 8; ++n) lg[e0 + n][lane] = acc[n];
    __syncthreads();

    // ---- phase 3: softmax + stable top-2 (wave 0), validated r1-r4 ----
    if (w == 0) {
        float l[NE];
#pragma unroll
        for (int e = 0; e < NE; ++e) l[e] = lg[e][lane];

        float mx = l[0];
#pragma unroll
        for (int e = 1; e < NE; ++e) mx = fmaxf(mx, l[e]);

        float ssum = 0.f;
#pragma unroll
        for (int e = 0; e < NE; ++e) { float p = expf(l[e] - mx); l[e] = p; ssum += p; }
        const float inv = 1.0f / ssum;
#pragma unroll
        for (int e = 0; e < NE; ++e) l[e] *= inv;

        float v1 = -1.0f, v2 = -2.0f;
        int   i1 = 0,     i2 = 0;
#pragma unroll
        for (int e = 0; e < NE; ++e) {
            const float p  = l[e];
            const bool  g1 = p > v1;
            const bool  g2 = p > v2;
            const float nv2 = g1 ? v1 : (g2 ? p : v2);
            const int   ni2 = g1 ? i1 : (g2 ? e : i2);
            v1 = g1 ? p : v1;
            i1 = g1 ? e : i1;
            v2 = nv2;
            i2 = ni2;
        }

        const int row = r0 + lane;
        float* out_idx  = out;
        float* out_gate = out + 2 * NTOK;
        float* out_prob = out + 4 * NTOK;
        out_idx[2 * row + 0]  = (float)i1;
        out_idx[2 * row + 1]  = (float)i2;
        out_gate[2 * row + 0] = v1;
        out_gate[2 * row + 1] = v2;

        float* pr = out_prob + (size_t)row * NE;
#pragma unroll
        for (int e = 0; e < NE; e += 4)
            *(float4*)(pr + e) = make_float4(l[e], l[e + 1], l[e + 2], l[e + 3]);
    }
}

extern "C" void kernel_launch(void* const* d_in, const int* in_sizes, int n_in,
                              void* d_out, int out_size, void* d_ws, size_t ws_size,
                              hipStream_t stream) {
    const float* x  = (const float*)d_in[0];
    const float* w1 = (const float*)d_in[1];
    const float* b1 = (const float*)d_in[2];
    const float* w2 = (const float*)d_in[3];
    float* out = (float*)d_out;

    // workspace: w1t (4 MB) | P (32 MB)  = 36 MB
    unsigned short* w1t = (unsigned short*)d_ws;
    float* P = (float*)((char*)d_ws + (4u << 20));

    convert_w1_kernel<<<512, 512, 0, stream>>>(w1, w1t);
    gemm1_mfma_kernel<<<512, 512, 0, stream>>>(x, w1t, P);
    reduce_gate_kernel<<<128, 512, 0, stream>>>(P, b1, w2, out);
}

// Round 6
// 91.138 us; speedup vs baseline: 9.8332x; 1.3680x over previous
//
#include <hip/hip_runtime.h>
#include <hip/hip_bf16.h>
#include <math.h>

#define NTOK 8192
#define DIN  4096
#define HG   256
#define NE   64
#define SPLITK 4
#define KSTEPS 32          // ksteps of 32 per split (4096/4/32)
#define TR   16            // rows per tail block

typedef __attribute__((ext_vector_type(8))) short short8;
typedef __attribute__((ext_vector_type(4))) short short4v;
typedef __attribute__((ext_vector_type(4))) float f32x4;

__device__ __forceinline__ unsigned short f2bf_rne(float f) {
    union { float f; unsigned int u; } v; v.f = f;
    unsigned int r = v.u + 0x7fffu + ((v.u >> 16) & 1u);
    return (unsigned short)(r >> 16);
}
__device__ __forceinline__ float bf2f(unsigned short b) {
    union { unsigned int u; float f; } v; v.u = ((unsigned int)b) << 16;
    return v.f;
}

typedef const __attribute__((address_space(1))) unsigned int* gptr_t;
typedef __attribute__((address_space(3))) unsigned int* lptr_t;
__device__ __forceinline__ void gload_lds16(const void* g, void* l) {
    __builtin_amdgcn_global_load_lds((gptr_t)g, (lptr_t)l, 16, 0, 0);
}

// ---------------------------------------------------------------------------
// Pre-convert w1 [HG][DIN] fp32 -> fragment-ordered bf16 hi/lo tiles.
// w1t[kstep][c][lane][j]: c = hl*16+unit; value = (hi|lo) of
// w1[unit*16 + (lane&15)][kstep*32 + (lane>>4)*8 + j].   (validated r3-r5)
// ---------------------------------------------------------------------------
__global__ __launch_bounds__(512) void convert_w1_kernel(
    const float* __restrict__ w1, unsigned short* __restrict__ w1t)
{
    const int id    = blockIdx.x * 512 + threadIdx.x;
    const int lane  = id & 63;
    const int cg    = id >> 6;           // 0..4095
    const int kstep = cg >> 5;
    const int c     = cg & 31;
    const int hl    = c >> 4;
    const int unit  = c & 15;
    const int n     = unit * 16 + (lane & 15);
    const int k     = kstep * 32 + ((lane >> 4) & 3) * 8;

    const float* src = w1 + (size_t)n * DIN + k;
    short8 v;
#pragma unroll
    for (int j = 0; j < 8; ++j) {
        float f = src[j];
        unsigned short hi = f2bf_rne(f);
        v[j] = (hl == 0) ? (short)hi : (short)f2bf_rne(f - bf2f(hi));
    }
    *(short8*)(w1t + (size_t)cg * 512 + lane * 8) = v;
}

// ---------------------------------------------------------------------------
// GEMM1 (split-K): P[s][NTOK][HG] = x(bf16x3) @ w1^T for k-range s.
// 512 blocks = 128 m-tiles (BM=64) x 4 splitK; 512 thr = 8 waves (2M x 4N of
// 32x64 wave tiles). LDS 72 KB -> 2 blocks/CU (4 waves/SIMD).
// (byte-identical to round 5 -- validated)
// ---------------------------------------------------------------------------
__global__ __launch_bounds__(512, 4) void gemm1_mfma_kernel(
    const float* __restrict__ x, const unsigned short* __restrict__ w1t,
    float* __restrict__ P)
{
    __shared__ unsigned short As[2][4][512];     // [hl][unit][slot*8+j] : 8 KB
    __shared__ unsigned short Bs[2][2][16][512]; // [buf][hl][unit][...] : 64 KB

    const int bid  = blockIdx.x;
    const int mblk = bid & 127;
    const int s    = bid >> 7;
    const int t    = threadIdx.x;
    const int lane = t & 63;
    const int w    = t >> 6;
    const int wm   = w >> 2;          // 0..1
    const int wn   = w & 3;           // 0..3

    const int m_base = mblk * 64;
    const int kstep0 = s * KSTEPS;

    const int a_unit = t >> 7;            // 0..3
    const int a_slot = (t >> 1) & 63;     // 0..63 : (kseg<<4)|row15
    const int a_half = t & 1;
    const int a_row  = a_unit * 16 + (a_slot & 15);
    const int a_koff = (a_slot >> 4) * 8 + a_half * 4;
    const float* asrc = x + (size_t)(m_base + a_row) * DIN
                          + (size_t)kstep0 * 32 + a_koff;
    const int a_ldso = a_slot * 8 + a_half * 4;

    f32x4 acc[2][4];
#pragma unroll
    for (int i = 0; i < 2; ++i)
#pragma unroll
        for (int j = 0; j < 4; ++j) acc[i][j] = (f32x4)0.f;

#define CVT4_STORE(F)                                                         \
    {   short4v vh_, vl_;                                                     \
        float ff_[4] = { (F).x, (F).y, (F).z, (F).w };                        \
        _Pragma("unroll")                                                     \
        for (int j_ = 0; j_ < 4; ++j_) {                                      \
            unsigned short h_ = f2bf_rne(ff_[j_]);                            \
            vh_[j_] = (short)h_;                                              \
            vl_[j_] = (short)f2bf_rne(ff_[j_] - bf2f(h_));                    \
        }                                                                     \
        *(short4v*)&As[0][a_unit][a_ldso] = vh_;                              \
        *(short4v*)&As[1][a_unit][a_ldso] = vl_;                              \
    }

#pragma unroll
    for (int i = 0; i < 4; ++i) {
        const int c = w * 4 + i;
        gload_lds16(w1t + ((size_t)kstep0 * 32 + c) * 512 + lane * 8,
                    &Bs[0][c >> 4][c & 15][0]);
    }
    {
        float4 a0 = *(const float4*)(asrc);
        CVT4_STORE(a0)
    }
    __syncthreads();

#pragma unroll 1
    for (int tt = 0; tt < KSTEPS; ++tt) {
        const int bcur = tt & 1, bnxt = bcur ^ 1;
        const bool last = (tt == KSTEPS - 1);

        float4 nx;
        if (!last) {
            nx = *(const float4*)(asrc + (size_t)(tt + 1) * 32);
#pragma unroll
            for (int i = 0; i < 4; ++i) {
                const int c = w * 4 + i;
                gload_lds16(w1t + ((size_t)(kstep0 + tt + 1) * 32 + c) * 512 + lane * 8,
                            &Bs[bnxt][c >> 4][c & 15][0]);
            }
        }

        short8 ahf[2], alf[2], bhf[4], blf[4];
#pragma unroll
        for (int mr = 0; mr < 2; ++mr) {
            ahf[mr] = *(const short8*)&As[0][wm * 2 + mr][lane * 8];
            alf[mr] = *(const short8*)&As[1][wm * 2 + mr][lane * 8];
        }
#pragma unroll
        for (int nr = 0; nr < 4; ++nr) {
            bhf[nr] = *(const short8*)&Bs[bcur][0][wn * 4 + nr][lane * 8];
            blf[nr] = *(const short8*)&Bs[bcur][1][wn * 4 + nr][lane * 8];
        }

#pragma unroll
        for (int mr = 0; mr < 2; ++mr)
#pragma unroll
            for (int nr = 0; nr < 4; ++nr)
                acc[mr][nr] = __builtin_amdgcn_mfma_f32_16x16x32_bf16(
                    ahf[mr], bhf[nr], acc[mr][nr], 0, 0, 0);
#pragma unroll
        for (int mr = 0; mr < 2; ++mr)
#pragma unroll
            for (int nr = 0; nr < 4; ++nr)
                acc[mr][nr] = __builtin_amdgcn_mfma_f32_16x16x32_bf16(
                    ahf[mr], blf[nr], acc[mr][nr], 0, 0, 0);
#pragma unroll
        for (int mr = 0; mr < 2; ++mr)
#pragma unroll
            for (int nr = 0; nr < 4; ++nr)
                acc[mr][nr] = __builtin_amdgcn_mfma_f32_16x16x32_bf16(
                    alf[mr], bhf[nr], acc[mr][nr], 0, 0, 0);

        if (!last) {
            __syncthreads();
            CVT4_STORE(nx)
            __syncthreads();
        }
    }
#undef CVT4_STORE

    float* pb = P + (size_t)s * ((size_t)NTOK * HG);
#pragma unroll
    for (int mr = 0; mr < 2; ++mr)
#pragma unroll
        for (int nr = 0; nr < 4; ++nr) {
            const int n = wn * 64 + nr * 16 + (lane & 15);
#pragma unroll
            for (int r = 0; r < 4; ++r) {
                const int m = m_base + wm * 32 + mr * 16 + ((lane >> 4) & 3) * 4 + r;
                pb[(size_t)m * HG + n] = acc[mr][nr][r];
            }
        }
}

// ---------------------------------------------------------------------------
// Fused tail v2: 512 blocks x 512 thr, TR=16 rows/block, 25 KB LDS ->
// 2 blocks/CU, 4 waves/SIMD, all CUs busy.
// Phase 1: reduce 4 split-K partials + bias + exact GELU -> h_lds[16][260]
//          (pad 260 -> bank-uniform b128 writes/reads).
// Phase 2: wave w -> experts [8w,8w+8); lane = (row=lane&15, kq=lane>>4)
//          quarter-K dot; __shfl_xor(16/32) reduce; lanes<16 write lg.
// Phase 3: lanes 0..15 of wave 0: softmax + stable top-2 (validated r1-r5).
// d_out = [ indices(float) N*2 | gates N*2 | probs N*64 ]
// ---------------------------------------------------------------------------
__global__ __launch_bounds__(512, 4) void reduce_gate_kernel(
    const float* __restrict__ P, const float* __restrict__ b1,
    const float* __restrict__ w2, float* __restrict__ out)
{
    __shared__ float h_lds[TR][260];
    __shared__ float lg[NE][33];

    const int t    = threadIdx.x;
    const int lane = t & 63;
    const int w    = t >> 6;
    const int r0   = blockIdx.x * TR;
    const size_t SS = (size_t)NTOK * HG;

    // ---- phase 1: reduce + bias + gelu (coalesced: 32 thr = one row) ----
    {
        const int row = t >> 5;          // 0..15
        const int sg  = t & 31;          // 8 floats at cols sg*8
        const size_t base = (size_t)(r0 + row) * HG + sg * 8;

        float q[8];
#pragma unroll
        for (int half = 0; half < 2; ++half) {
            float4 v0 = *(const float4*)(P + base + half * 4);
            float4 v1 = *(const float4*)(P + base + SS + half * 4);
            float4 v2 = *(const float4*)(P + base + 2 * SS + half * 4);
            float4 v3 = *(const float4*)(P + base + 3 * SS + half * 4);
            float4 bb = *(const float4*)(b1 + sg * 8 + half * 4);
            q[half * 4 + 0] = v0.x + v1.x + v2.x + v3.x + bb.x;
            q[half * 4 + 1] = v0.y + v1.y + v2.y + v3.y + bb.y;
            q[half * 4 + 2] = v0.z + v1.z + v2.z + v3.z + bb.z;
            q[half * 4 + 3] = v0.w + v1.w + v2.w + v3.w + bb.w;
        }
#pragma unroll
        for (int c = 0; c < 8; ++c)
            q[c] = 0.5f * q[c] * (1.0f + erff(q[c] * 0.70710678118654752440f));

        *(float4*)&h_lds[row][sg * 8]     = make_float4(q[0], q[1], q[2], q[3]);
        *(float4*)&h_lds[row][sg * 8 + 4] = make_float4(q[4], q[5], q[6], q[7]);
    }
    __syncthreads();

    // ---- phase 2: logits; wave w -> 8 experts, quarter-K per lane ----
    const int e0   = w * 8;
    const int rowp = lane & 15;
    const int kq   = lane >> 4;          // 0..3 -> k-range kq*64

    float acc[8];
#pragma unroll
    for (int i = 0; i < 8; ++i) acc[i] = 0.f;

    const float* w2b = w2 + (size_t)e0 * HG + kq * 64;
#pragma unroll 1
    for (int kc = 0; kc < 64; kc += 8) {
        float a[8];
        *(float4*)&a[0] = *(const float4*)&h_lds[rowp][kq * 64 + kc];
        *(float4*)&a[4] = *(const float4*)&h_lds[rowp][kq * 64 + kc + 4];
#pragma unroll
        for (int n = 0; n < 8; ++n) {
            const float* wr = w2b + (size_t)n * HG + kc;
            float4 w0 = *(const float4*)(wr);
            float4 w1v = *(const float4*)(wr + 4);
            acc[n] = fmaf(w0.x, a[0], acc[n]);
            acc[n] = fmaf(w0.y, a[1], acc[n]);
            acc[n] = fmaf(w0.z, a[2], acc[n]);
            acc[n] = fmaf(w0.w, a[3], acc[n]);
            acc[n] = fmaf(w1v.x, a[4], acc[n]);
            acc[n] = fmaf(w1v.y, a[5], acc[n]);
            acc[n] = fmaf(w1v.z, a[6], acc[n]);
            acc[n] = fmaf(w1v.w, a[7], acc[n]);
        }
    }
#pragma unroll
    for (int n = 0; n < 8; ++n) {
        acc[n] += __shfl_xor(acc[n], 16);
        acc[n] += __shfl_xor(acc[n], 32);
    }
    if (lane < 16) {
#pragma unroll
        for (int n = 0; n < 8; ++n) lg[e0 + n][rowp] = acc[n];
    }
    __syncthreads();

    // ---- phase 3: softmax + stable top-2 (lanes 0..15 of wave 0) ----
    if (t < TR) {
        float l[NE];
#pragma unroll
        for (int e = 0; e < NE; ++e) l[e] = lg[e][t];

        float mx = l[0];
#pragma unroll
        for (int e = 1; e < NE; ++e) mx = fmaxf(mx, l[e]);

        float ssum = 0.f;
#pragma unroll
        for (int e = 0; e < NE; ++e) { float p = expf(l[e] - mx); l[e] = p; ssum += p; }
        const float inv = 1.0f / ssum;
#pragma unroll
        for (int e = 0; e < NE; ++e) l[e] *= inv;

        float v1 = -1.0f, v2 = -2.0f;
        int   i1 = 0,     i2 = 0;
#pragma unroll
        for (int e = 0; e < NE; ++e) {
            const float p  = l[e];
            const bool  g1 = p > v1;
            const bool  g2 = p > v2;
            const float nv2 = g1 ? v1 : (g2 ? p : v2);
            const int   ni2 = g1 ? i1 : (g2 ? e : i2);
            v1 = g1 ? p : v1;
            i1 = g1 ? e : i1;
            v2 = nv2;
            i2 = ni2;
        }

        const int row = r0 + t;
        float* out_idx  = out;
        float* out_gate = out + 2 * NTOK;
        float* out_prob = out + 4 * NTOK;
        out_idx[2 * row + 0]  = (float)i1;
        out_idx[2 * row + 1]  = (float)i2;
        out_gate[2 * row + 0] = v1;
        out_gate[2 * row + 1] = v2;

        float* pr = out_prob + (size_t)row * NE;
#pragma unroll
        for (int e = 0; e < NE; e += 4)
            *(float4*)(pr + e) = make_float4(l[e], l[e + 1], l[e + 2], l[e + 3]);
    }
}

extern "C" void kernel_launch(void* const* d_in, const int* in_sizes, int n_in,
                              void* d_out, int out_size, void* d_ws, size_t ws_size,
                              hipStream_t stream) {
    const float* x  = (const float*)d_in[0];
    const float* w1 = (const float*)d_in[1];
    const float* b1 = (const float*)d_in[2];
    const float* w2 = (const float*)d_in[3];
    float* out = (float*)d_out;

    // workspace: w1t (4 MB) | P (32 MB)  = 36 MB
    unsigned short* w1t = (unsigned short*)d_ws;
    float* P = (float*)((char*)d_ws + (4u << 20));

    convert_w1_kernel<<<512, 512, 0, stream>>>(w1, w1t);
    gemm1_mfma_kernel<<<512, 512, 0, stream>>>(x, w1t, P);
    reduce_gate_kernel<<<512, 512, 0, stream>>>(P, b1, w2, out);
}